// Round 1
// baseline (218.857 us; speedup 1.0000x reference)
//
#include <hip/hip_runtime.h>
#include <cstddef>

#define NB 64
#define NL 4096
#define ND 512
#define NDP 64
#define NCHUNK 32
#define LCHUNK (NL / NCHUNK)  // 128

// ---------------------------------------------------------------------------
// Kernel 1: q_main[b,d] = sum_e source[b,e]*Wmi[e,d]
//           q_pos [b,p] = sum_d source[b,d]*Wpi[d,p]
// ---------------------------------------------------------------------------
__global__ void __launch_bounds__(256) queries_kernel(
    const float* __restrict__ source, const float* __restrict__ Wmi,
    const float* __restrict__ Wpi, float* __restrict__ q_main,
    float* __restrict__ q_pos)
{
    __shared__ float s[ND];
    const int b = blockIdx.x;
    const int tid = threadIdx.x;
    for (int i = tid; i < ND; i += 256) s[i] = source[b * ND + i];
    __syncthreads();
    for (int d = tid; d < ND; d += 256) {
        float acc = 0.f;
        for (int e = 0; e < ND; ++e) acc = fmaf(s[e], Wmi[e * ND + d], acc);
        q_main[b * ND + d] = acc;
    }
    if (tid < NDP) {
        float acc = 0.f;
        for (int d = 0; d < ND; ++d) acc = fmaf(s[d], Wpi[d * NDP + tid], acc);
        q_pos[b * NDP + tid] = acc;
    }
}

// ---------------------------------------------------------------------------
// Kernel 2: alignments. One wave per (l,b) row in memory order r = l*NB + b.
// Skips masked rows (l >= len[b]); writes raw aligns into ma/pa out-slots.
// ---------------------------------------------------------------------------
__global__ void __launch_bounds__(256) align_kernel(
    const float* __restrict__ me, const float* __restrict__ pe,
    const float* __restrict__ q_main, const float* __restrict__ q_pos,
    const int* __restrict__ mem_len,
    float* __restrict__ a_main, float* __restrict__ a_pos)
{
    const int gtid = blockIdx.x * blockDim.x + threadIdx.x;
    const int wave = gtid >> 6;
    const int lane = threadIdx.x & 63;
    const int nwaves = (gridDim.x * blockDim.x) >> 6;

    for (int r = wave; r < NL * NB; r += nwaves) {
        const int b = r & (NB - 1);
        const int l = r >> 6;
        if (l >= mem_len[b]) continue;   // masked -> softmax output is 0; skip bytes

        const float4* mrow = (const float4*)(me + (size_t)r * ND);
        const float4* qrow = (const float4*)(q_main + b * ND);
        const float4 m0 = mrow[lane];
        const float4 m1 = mrow[64 + lane];
        const float4 q0 = qrow[lane];
        const float4 q1 = qrow[64 + lane];
        float accm = m0.x * q0.x + m0.y * q0.y + m0.z * q0.z + m0.w * q0.w
                   + m1.x * q1.x + m1.y * q1.y + m1.z * q1.z + m1.w * q1.w;
        float accp = pe[(size_t)r * NDP + lane] * q_pos[b * NDP + lane];

        #pragma unroll
        for (int off = 32; off; off >>= 1) {
            accm += __shfl_xor(accm, off);
            accp += __shfl_xor(accp, off);
        }
        if (lane == 0) {
            a_main[(size_t)b * NL + l] = accm;
            a_pos[(size_t)b * NL + l] = accp;
        }
    }
}

// ---------------------------------------------------------------------------
// Kernel 3: three masked softmaxes per b, in place on ma/pa; av = softmax(a+p).
// ---------------------------------------------------------------------------
__global__ void __launch_bounds__(1024) softmax_kernel(
    const int* __restrict__ mem_len,
    float* __restrict__ out_av, float* ma_io, float* pa_io)
{
    __shared__ float red[16 * 3];
    const int b = blockIdx.x;
    const int tid = threadIdx.x;
    const int len = mem_len[b];
    const int wid = tid >> 6, lane = tid & 63;

    float va[4], vp[4];
    float m_a = -1e30f, m_p = -1e30f, m_c = -1e30f;
    #pragma unroll
    for (int k = 0; k < 4; ++k) {
        const int l = tid + k * 1024;
        const float a = ma_io[(size_t)b * NL + l];
        const float p = pa_io[(size_t)b * NL + l];
        va[k] = a; vp[k] = p;
        if (l < len) {
            m_a = fmaxf(m_a, a);
            m_p = fmaxf(m_p, p);
            m_c = fmaxf(m_c, a + p);
        }
    }
    #pragma unroll
    for (int off = 32; off; off >>= 1) {
        m_a = fmaxf(m_a, __shfl_xor(m_a, off));
        m_p = fmaxf(m_p, __shfl_xor(m_p, off));
        m_c = fmaxf(m_c, __shfl_xor(m_c, off));
    }
    if (lane == 0) { red[wid*3+0] = m_a; red[wid*3+1] = m_p; red[wid*3+2] = m_c; }
    __syncthreads();
    if (tid == 0) {
        for (int i = 1; i < 16; ++i) {
            red[0] = fmaxf(red[0], red[i*3+0]);
            red[1] = fmaxf(red[1], red[i*3+1]);
            red[2] = fmaxf(red[2], red[i*3+2]);
        }
    }
    __syncthreads();
    m_a = red[0]; m_p = red[1]; m_c = red[2];
    __syncthreads();

    float ea[4], ep[4], ec[4];
    float s_a = 0.f, s_p = 0.f, s_c = 0.f;
    #pragma unroll
    for (int k = 0; k < 4; ++k) {
        const int l = tid + k * 1024;
        const bool v = l < len;
        ea[k] = v ? expf(va[k] - m_a) : 0.f;
        ep[k] = v ? expf(vp[k] - m_p) : 0.f;
        ec[k] = v ? expf(va[k] + vp[k] - m_c) : 0.f;
        s_a += ea[k]; s_p += ep[k]; s_c += ec[k];
    }
    #pragma unroll
    for (int off = 32; off; off >>= 1) {
        s_a += __shfl_xor(s_a, off);
        s_p += __shfl_xor(s_p, off);
        s_c += __shfl_xor(s_c, off);
    }
    if (lane == 0) { red[wid*3+0] = s_a; red[wid*3+1] = s_p; red[wid*3+2] = s_c; }
    __syncthreads();
    if (tid == 0) {
        for (int i = 1; i < 16; ++i) {
            red[0] += red[i*3+0];
            red[1] += red[i*3+1];
            red[2] += red[i*3+2];
        }
    }
    __syncthreads();
    const float ra = 1.f / red[0], rp = 1.f / red[1], rc = 1.f / red[2];

    #pragma unroll
    for (int k = 0; k < 4; ++k) {
        const int l = tid + k * 1024;
        ma_io[(size_t)b * NL + l] = ea[k] * ra;
        pa_io[(size_t)b * NL + l] = ep[k] * rp;
        out_av[(size_t)b * NL + l] = ec[k] * rc;
    }
}

// ---------------------------------------------------------------------------
// Kernel 4: partial context sums. Block (b, chunk): acc[d] += av[b,l]*me[l,b,d]
// over its l-chunk (clipped to len[b]). Deterministic two-stage reduction.
// ---------------------------------------------------------------------------
__global__ void __launch_bounds__(256) ctx_partial_kernel(
    const float* __restrict__ me, const float* __restrict__ av,
    const int* __restrict__ mem_len, float* __restrict__ partial)
{
    const int b = blockIdx.x & (NB - 1);
    const int chunk = blockIdx.x >> 6;
    const int tid = threadIdx.x;
    const int len = mem_len[b];
    const int l0 = chunk * LCHUNK;
    const int lend = min(l0 + LCHUNK, len);

    float2 acc = {0.f, 0.f};
    for (int l = l0; l < lend; ++l) {
        const float w = av[(size_t)b * NL + l];
        const float2 v = ((const float2*)(me + ((size_t)l * NB + b) * ND))[tid];
        acc.x = fmaf(w, v.x, acc.x);
        acc.y = fmaf(w, v.y, acc.y);
    }
    ((float2*)(partial + ((size_t)b * NCHUNK + chunk) * ND))[tid] = acc;
}

// ---------------------------------------------------------------------------
// Kernel 5: c_t = sum chunks; attn_h[b,e] = tanh(<[c_t,source], W_out[e,:]>)
// Block = (b, e-group of 64). Wave-per-e dot product over 1024 elems.
// ---------------------------------------------------------------------------
__global__ void __launch_bounds__(256) out_kernel(
    const float* __restrict__ partial, const float* __restrict__ source,
    const float* __restrict__ Wout, float* __restrict__ attn_h)
{
    __shared__ float cs[2 * ND];
    const int b = blockIdx.x >> 3;
    const int eg = blockIdx.x & 7;
    const int tid = threadIdx.x;

    for (int d = tid; d < ND; d += 256) {
        float acc = 0.f;
        for (int c = 0; c < NCHUNK; ++c)
            acc += partial[((size_t)b * NCHUNK + c) * ND + d];
        cs[d] = acc;
        cs[ND + d] = source[b * ND + d];
    }
    __syncthreads();

    const int wid = tid >> 6, lane = tid & 63;
    const float4* csv = (const float4*)cs;
    for (int e = eg * 64 + wid; e < eg * 64 + 64; e += 4) {
        const float4* wrow = (const float4*)(Wout + (size_t)e * 2 * ND);
        float acc = 0.f;
        #pragma unroll
        for (int j = 0; j < 4; ++j) {
            const float4 w = wrow[lane + 64 * j];
            const float4 c = csv[lane + 64 * j];
            acc += w.x * c.x + w.y * c.y + w.z * c.z + w.w * c.w;
        }
        #pragma unroll
        for (int off = 32; off; off >>= 1) acc += __shfl_xor(acc, off);
        if (lane == 0) attn_h[(size_t)b * ND + e] = tanhf(acc);
    }
}

// ---------------------------------------------------------------------------
extern "C" void kernel_launch(void* const* d_in, const int* in_sizes, int n_in,
                              void* d_out, int out_size, void* d_ws, size_t ws_size,
                              hipStream_t stream)
{
    const float* source = (const float*)d_in[0];
    const float* me     = (const float*)d_in[1];   // (L, B, D)
    const float* pe     = (const float*)d_in[2];   // (L, B, DP)
    const float* Wmi    = (const float*)d_in[3];   // (D, D)
    const float* Wpi    = (const float*)d_in[4];   // (D, DP)
    const float* Wout   = (const float*)d_in[5];   // (D, 2D)
    const int*   lens   = (const int*)d_in[6];     // (B,)

    float* out    = (float*)d_out;
    float* attn_h = out;                    // (B, D)
    float* av     = attn_h + NB * ND;       // (B, L)
    float* ma     = av + NB * NL;           // (B, L)
    float* pa     = ma + NB * NL;           // (B, L)

    float* ws      = (float*)d_ws;
    float* q_main  = ws;                    // NB*ND   = 32768 floats
    float* q_pos   = q_main + NB * ND;      // NB*NDP  = 4096
    float* partial = q_pos + NB * NDP;      // NB*NCHUNK*ND = 1048576

    queries_kernel<<<NB, 256, 0, stream>>>(source, Wmi, Wpi, q_main, q_pos);
    align_kernel<<<2048, 256, 0, stream>>>(me, pe, q_main, q_pos, lens, ma, pa);
    softmax_kernel<<<NB, 1024, 0, stream>>>(lens, av, ma, pa);
    ctx_partial_kernel<<<NB * NCHUNK, 256, 0, stream>>>(me, av, lens, partial);
    out_kernel<<<NB * 8, 256, 0, stream>>>(partial, source, Wout, attn_h);
}

// Round 2
// 156.221 us; speedup vs baseline: 1.4009x; 1.4009x over previous
//
#include <hip/hip_runtime.h>
#include <cstddef>

#define NB 64
#define NL 4096
#define ND 512
#define NDP 64
#define LC 64                 // l-rows per chunk (per wave in pass1)
#define NLC (NL / LC)         // 64 chunks per b

// ---------------------------------------------------------------------------
// Kernel 1: q_main[b,d] = sum_e source[b,e]*Wmi[e,d]
//           q_pos [b,p] = sum_d source[b,d]*Wpi[d,p]
// ---------------------------------------------------------------------------
__global__ void __launch_bounds__(256) queries_kernel(
    const float* __restrict__ source, const float* __restrict__ Wmi,
    const float* __restrict__ Wpi, float* __restrict__ q_main,
    float* __restrict__ q_pos)
{
    __shared__ float s[ND];
    const int b = blockIdx.x;
    const int tid = threadIdx.x;
    for (int i = tid; i < ND; i += 256) s[i] = source[b * ND + i];
    __syncthreads();
    for (int d = tid; d < ND; d += 256) {
        float acc = 0.f;
        for (int e = 0; e < ND; ++e) acc = fmaf(s[e], Wmi[e * ND + d], acc);
        q_main[b * ND + d] = acc;
    }
    if (tid < NDP) {
        float acc = 0.f;
        for (int d = 0; d < ND; ++d) acc = fmaf(s[d], Wpi[d * NDP + tid], acc);
        q_pos[b * NDP + tid] = acc;
    }
}

// ---------------------------------------------------------------------------
// Kernel 2 (fused): per wave = (b, l-chunk of LC rows).
//  - dot(q_main, me_row) + dot(q_pos, pe_row) -> raw aligns (stored)
//  - online softmax-weighted row sum: running {m, Z, S[8]/lane} in registers.
// Block layout is lc-major so the block->CU round-robin stratifies l
// (work is triangular in l) -> balanced CU load.
// ---------------------------------------------------------------------------
__global__ void __launch_bounds__(256) pass1_kernel(
    const float* __restrict__ me, const float* __restrict__ pe,
    const float* __restrict__ q_main, const float* __restrict__ q_pos,
    const int* __restrict__ mem_len,
    float* __restrict__ a_main, float* __restrict__ a_pos,
    float* __restrict__ Sbuf, float* __restrict__ MZ)
{
    const int lane = threadIdx.x & 63;
    const int wid  = threadIdx.x >> 6;
    const int lc = blockIdx.x >> 4;          // 64 chunks
    const int b  = (blockIdx.x & 15) * 4 + wid;

    const int len = mem_len[b];
    const int l0 = lc * LC;
    const int lend = min(l0 + LC, len);

    const float4* qrow = (const float4*)(q_main + b * ND);
    const float4 q0 = qrow[lane];
    const float4 q1 = qrow[64 + lane];
    const float  qp = q_pos[b * NDP + lane];

    float m = -1e30f, Z = 0.f;
    float4 S0 = {0.f, 0.f, 0.f, 0.f};
    float4 S1 = {0.f, 0.f, 0.f, 0.f};

    for (int l = l0; l < lend; ++l) {
        const size_t r = (size_t)l * NB + b;
        const float4* mrow = (const float4*)(me + r * ND);
        const float4 m0 = mrow[lane];
        const float4 m1 = mrow[64 + lane];

        float accm = m0.x*q0.x + m0.y*q0.y + m0.z*q0.z + m0.w*q0.w
                   + m1.x*q1.x + m1.y*q1.y + m1.z*q1.z + m1.w*q1.w;
        float accp = pe[r * NDP + lane] * qp;
        #pragma unroll
        for (int off = 32; off; off >>= 1) {
            accm += __shfl_xor(accm, off);
            accp += __shfl_xor(accp, off);
        }
        if (lane == 0) {
            a_main[(size_t)b * NL + l] = accm;
            a_pos [(size_t)b * NL + l] = accp;
        }

        const float s  = accm + accp;
        const float mn = fmaxf(m, s);
        const float sc = __expf(m - mn);
        const float w  = __expf(s - mn);
        Z = Z * sc + w;
        S0.x = S0.x * sc + w * m0.x;  S0.y = S0.y * sc + w * m0.y;
        S0.z = S0.z * sc + w * m0.z;  S0.w = S0.w * sc + w * m0.w;
        S1.x = S1.x * sc + w * m1.x;  S1.y = S1.y * sc + w * m1.y;
        S1.z = S1.z * sc + w * m1.z;  S1.w = S1.w * sc + w * m1.w;
        m = mn;
    }

    float* sp = Sbuf + ((size_t)b * NLC + lc) * ND;
    ((float4*)sp)[lane]      = S0;
    ((float4*)sp)[64 + lane] = S1;
    if (lane == 0) {
        MZ[(b * NLC + lc) * 2 + 0] = m;
        MZ[(b * NLC + lc) * 2 + 1] = Z;
    }
}

// ---------------------------------------------------------------------------
// Kernel 3: per-b combine. c_t from chunk partials (associative flash combine;
// the combined (M, Z) are exactly av's softmax stats). Also reduces (Ma,Za),
// (Mp,Zp) from the raw aligns.
// ---------------------------------------------------------------------------
__global__ void __launch_bounds__(256) combine_kernel(
    const float* __restrict__ Sbuf, const float* __restrict__ MZ,
    const float* __restrict__ a_main, const float* __restrict__ a_pos,
    const int* __restrict__ mem_len,
    float* __restrict__ c_t, float* __restrict__ stats)
{
    const int b = blockIdx.x;
    const int tid = threadIdx.x;
    const int lane = tid & 63, wid = tid >> 6;
    __shared__ float shm[4][2];
    __shared__ float shs[4][2];

    // --- combined max over chunks (every wave computes it; lane covers NLC=64)
    float mloc = MZ[(b * NLC + lane) * 2];
    #pragma unroll
    for (int off = 32; off; off >>= 1) mloc = fmaxf(mloc, __shfl_xor(mloc, off));
    const float M = mloc;

    float Zacc = 0.f;
    float cx = 0.f, cy = 0.f;
    for (int lc = 0; lc < NLC; ++lc) {
        const float2 mz = ((const float2*)MZ)[b * NLC + lc];
        const float sc = __expf(mz.x - M);
        Zacc += mz.y * sc;
        const float2 sv = ((const float2*)(Sbuf + ((size_t)(b * NLC + lc)) * ND))[tid];
        cx += sv.x * sc;
        cy += sv.y * sc;
    }
    const float invZ = 1.f / Zacc;
    c_t[b * ND + 2 * tid + 0] = cx * invZ;
    c_t[b * ND + 2 * tid + 1] = cy * invZ;

    // --- (Ma,Za), (Mp,Zp) over raw aligns
    const int len = mem_len[b];
    float Ma = -1e30f, Mp = -1e30f;
    for (int l = tid; l < NL; l += 256) {
        if (l < len) {
            Ma = fmaxf(Ma, a_main[(size_t)b * NL + l]);
            Mp = fmaxf(Mp, a_pos [(size_t)b * NL + l]);
        }
    }
    #pragma unroll
    for (int off = 32; off; off >>= 1) {
        Ma = fmaxf(Ma, __shfl_xor(Ma, off));
        Mp = fmaxf(Mp, __shfl_xor(Mp, off));
    }
    if (lane == 0) { shm[wid][0] = Ma; shm[wid][1] = Mp; }
    __syncthreads();
    Ma = fmaxf(fmaxf(shm[0][0], shm[1][0]), fmaxf(shm[2][0], shm[3][0]));
    Mp = fmaxf(fmaxf(shm[0][1], shm[1][1]), fmaxf(shm[2][1], shm[3][1]));

    float Za = 0.f, Zp = 0.f;
    for (int l = tid; l < NL; l += 256) {
        if (l < len) {
            Za += __expf(a_main[(size_t)b * NL + l] - Ma);
            Zp += __expf(a_pos [(size_t)b * NL + l] - Mp);
        }
    }
    #pragma unroll
    for (int off = 32; off; off >>= 1) {
        Za += __shfl_xor(Za, off);
        Zp += __shfl_xor(Zp, off);
    }
    if (lane == 0) { shs[wid][0] = Za; shs[wid][1] = Zp; }
    __syncthreads();
    Za = shs[0][0] + shs[1][0] + shs[2][0] + shs[3][0];
    Zp = shs[0][1] + shs[1][1] + shs[2][1] + shs[3][1];

    if (tid == 0) {
        stats[b * 8 + 0] = Ma;  stats[b * 8 + 1] = 1.f / Za;
        stats[b * 8 + 2] = Mp;  stats[b * 8 + 3] = 1.f / Zp;
        stats[b * 8 + 4] = M;   stats[b * 8 + 5] = invZ;
    }
}

// ---------------------------------------------------------------------------
// Kernel 4: finalize ma/pa/av elementwise (in place over raw aligns).
// ---------------------------------------------------------------------------
__global__ void __launch_bounds__(256) finalize_kernel(
    float* __restrict__ a_main, float* __restrict__ a_pos,
    float* __restrict__ out_av,
    const float* __restrict__ stats, const int* __restrict__ mem_len)
{
    const int idx = blockIdx.x * 256 + threadIdx.x;   // grid covers NB*NL exactly
    const int b = idx >> 12;
    const int l = idx & (NL - 1);
    const float* st = stats + b * 8;
    const int len = mem_len[b];
    const float a = a_main[idx];
    const float p = a_pos[idx];
    const bool v = l < len;
    a_main[idx] = v ? __expf(a - st[0]) * st[1] : 0.f;
    a_pos [idx] = v ? __expf(p - st[2]) * st[3] : 0.f;
    out_av[idx] = v ? __expf(a + p - st[4]) * st[5] : 0.f;
}

// ---------------------------------------------------------------------------
// Kernel 5: attn_h[b,e] = tanh(<[c_t,source], W_out[e,:]>)
// ---------------------------------------------------------------------------
__global__ void __launch_bounds__(256) out_kernel(
    const float* __restrict__ c_t, const float* __restrict__ source,
    const float* __restrict__ Wout, float* __restrict__ attn_h)
{
    __shared__ float cs[2 * ND];
    const int b = blockIdx.x >> 3;
    const int eg = blockIdx.x & 7;
    const int tid = threadIdx.x;

    for (int d = tid; d < ND; d += 256) {
        cs[d] = c_t[b * ND + d];
        cs[ND + d] = source[b * ND + d];
    }
    __syncthreads();

    const int wid = tid >> 6, lane = tid & 63;
    const float4* csv = (const float4*)cs;
    for (int e = eg * 64 + wid; e < eg * 64 + 64; e += 4) {
        const float4* wrow = (const float4*)(Wout + (size_t)e * 2 * ND);
        float acc = 0.f;
        #pragma unroll
        for (int j = 0; j < 4; ++j) {
            const float4 w = wrow[lane + 64 * j];
            const float4 c = csv[lane + 64 * j];
            acc += w.x * c.x + w.y * c.y + w.z * c.z + w.w * c.w;
        }
        #pragma unroll
        for (int off = 32; off; off >>= 1) acc += __shfl_xor(acc, off);
        if (lane == 0) attn_h[(size_t)b * ND + e] = tanhf(acc);
    }
}

// ---------------------------------------------------------------------------
extern "C" void kernel_launch(void* const* d_in, const int* in_sizes, int n_in,
                              void* d_out, int out_size, void* d_ws, size_t ws_size,
                              hipStream_t stream)
{
    const float* source = (const float*)d_in[0];
    const float* me     = (const float*)d_in[1];   // (L, B, D)
    const float* pe     = (const float*)d_in[2];   // (L, B, DP)
    const float* Wmi    = (const float*)d_in[3];   // (D, D)
    const float* Wpi    = (const float*)d_in[4];   // (D, DP)
    const float* Wout   = (const float*)d_in[5];   // (D, 2D)
    const int*   lens   = (const int*)d_in[6];     // (B,)

    float* out    = (float*)d_out;
    float* attn_h = out;                    // (B, D)
    float* av     = attn_h + NB * ND;       // (B, L)
    float* ma     = av + NB * NL;           // (B, L) — raw a_main, then in-place
    float* pa     = ma + NB * NL;           // (B, L) — raw a_pos,  then in-place

    float* ws     = (float*)d_ws;
    float* q_main = ws;                          // NB*ND        = 32768
    float* q_pos  = q_main + NB * ND;            // NB*NDP       = 4096
    float* Sbuf   = q_pos + NB * NDP;            // NB*NLC*ND    = 2097152
    float* MZ     = Sbuf + (size_t)NB * NLC * ND; // NB*NLC*2    = 8192
    float* c_t    = MZ + NB * NLC * 2;           // NB*ND        = 32768
    float* stats  = c_t + NB * ND;               // NB*8         = 512

    queries_kernel <<<NB, 256, 0, stream>>>(source, Wmi, Wpi, q_main, q_pos);
    pass1_kernel   <<<NLC * 16, 256, 0, stream>>>(me, pe, q_main, q_pos, lens,
                                                  ma, pa, Sbuf, MZ);
    combine_kernel <<<NB, 256, 0, stream>>>(Sbuf, MZ, ma, pa, lens, c_t, stats);
    finalize_kernel<<<NB * NL / 256, 256, 0, stream>>>(ma, pa, av, stats, lens);
    out_kernel     <<<NB * 8, 256, 0, stream>>>(c_t, source, Wout, attn_h);
}

// Round 3
// 119.714 us; speedup vs baseline: 1.8282x; 1.3050x over previous
//
#include <hip/hip_runtime.h>
#include <cstddef>

#define NB 64
#define NL 4096
#define ND 512
#define NDP 64
#define LC 64
#define NLC (NL / LC)   // 64

// ---------------------------------------------------------------------------
// K1: partial queries. Block = (b, eq), 256 blocks x 128 threads.
// qpm[(b*4+eq)*ND + d]  = sum_{e in seg} source[b,e]*Wmi[e,d]
// qpp[(b*4+eq)*NDP + p] = sum_{e in seg} source[b,e]*Wpi[e,p]
// ---------------------------------------------------------------------------
__global__ void __launch_bounds__(128) queries_kernel(
    const float* __restrict__ source, const float* __restrict__ Wmi,
    const float* __restrict__ Wpi, float* __restrict__ qpm,
    float* __restrict__ qpp)
{
    __shared__ float s[128];
    const int b  = blockIdx.x >> 2;
    const int eq = blockIdx.x & 3;
    const int t  = threadIdx.x;
    const int e0 = eq * 128;
    s[t] = source[b * ND + e0 + t];
    __syncthreads();

    const int d0 = t * 4;
    float4 a0 = {0,0,0,0}, a1 = {0,0,0,0};
    #pragma unroll 4
    for (int e = 0; e < 128; e += 2) {
        const float4 w0 = *(const float4*)(Wmi + (size_t)(e0 + e) * ND + d0);
        const float4 w1 = *(const float4*)(Wmi + (size_t)(e0 + e + 1) * ND + d0);
        const float x0 = s[e], x1 = s[e + 1];
        a0.x = fmaf(x0, w0.x, a0.x); a0.y = fmaf(x0, w0.y, a0.y);
        a0.z = fmaf(x0, w0.z, a0.z); a0.w = fmaf(x0, w0.w, a0.w);
        a1.x = fmaf(x1, w1.x, a1.x); a1.y = fmaf(x1, w1.y, a1.y);
        a1.z = fmaf(x1, w1.z, a1.z); a1.w = fmaf(x1, w1.w, a1.w);
    }
    a0.x += a1.x; a0.y += a1.y; a0.z += a1.z; a0.w += a1.w;
    *(float4*)(qpm + (size_t)(b * 4 + eq) * ND + d0) = a0;

    if (t < NDP) {
        float c0 = 0.f, c1 = 0.f;
        #pragma unroll 4
        for (int e = 0; e < 128; e += 2) {
            c0 = fmaf(s[e],     Wpi[(size_t)(e0 + e) * NDP + t],     c0);
            c1 = fmaf(s[e + 1], Wpi[(size_t)(e0 + e + 1) * NDP + t], c1);
        }
        qpp[(b * 4 + eq) * NDP + t] = c0 + c1;
    }
}

// ---------------------------------------------------------------------------
// K2: fused scorer + online stats. Wave = (b, lc chunk of LC rows).
//  - raw aligns written
//  - online (m,Z,S[8]/lane) for av-weighted context sum
//  - online (Ma,Za),(Mp,Zp) scalar stats for the two branch softmaxes
// b-swizzle: bg' = (bg + (lc>>4)) & 15 -> each CU serves 16 distinct b's.
// ---------------------------------------------------------------------------
__global__ void __launch_bounds__(256) pass1_kernel(
    const float* __restrict__ me, const float* __restrict__ pe,
    const float* __restrict__ qpm, const float* __restrict__ qpp,
    const int* __restrict__ mem_len,
    float* __restrict__ a_main, float* __restrict__ a_pos,
    float* __restrict__ Sbuf, float* __restrict__ MZ,
    float* __restrict__ MZa, float* __restrict__ MZp)
{
    const int lane = threadIdx.x & 63;
    const int wid  = threadIdx.x >> 6;
    const int bg   = blockIdx.x & 15;
    const int lc   = blockIdx.x >> 4;
    const int b    = (((bg + (lc >> 4)) & 15) << 2) | wid;

    const int len = mem_len[b];
    const int l0  = lc * LC;
    if (l0 >= len) return;
    const int lend = min(l0 + LC, len);

    // sum the 4 e-segment query partials (L2-resident, ~144B/wave)
    float4 q0 = {0,0,0,0}, q1 = {0,0,0,0};
    float qp = 0.f;
    #pragma unroll
    for (int eq = 0; eq < 4; ++eq) {
        const float4* qr = (const float4*)(qpm + (size_t)(b * 4 + eq) * ND);
        const float4 u0 = qr[lane], u1 = qr[64 + lane];
        q0.x += u0.x; q0.y += u0.y; q0.z += u0.z; q0.w += u0.w;
        q1.x += u1.x; q1.y += u1.y; q1.z += u1.z; q1.w += u1.w;
        qp += qpp[(b * 4 + eq) * NDP + lane];
    }

    float m = -1e30f, Z = 0.f;
    float Ma = -1e30f, Za = 0.f, Mp = -1e30f, Zp = 0.f;
    float4 S0 = {0,0,0,0}, S1 = {0,0,0,0};

    for (int l = l0; l < lend; ++l) {
        const size_t r = (size_t)l * NB + b;
        const float4* mrow = (const float4*)(me + r * ND);
        const float4 m0 = mrow[lane];
        const float4 m1 = mrow[64 + lane];

        float accm = m0.x*q0.x + m0.y*q0.y + m0.z*q0.z + m0.w*q0.w
                   + m1.x*q1.x + m1.y*q1.y + m1.z*q1.z + m1.w*q1.w;
        float accp = pe[r * NDP + lane] * qp;
        #pragma unroll
        for (int off = 32; off; off >>= 1) {
            accm += __shfl_xor(accm, off);
            accp += __shfl_xor(accp, off);
        }
        if (lane == 0) {
            a_main[(size_t)b * NL + l] = accm;
            a_pos [(size_t)b * NL + l] = accp;
        }

        // combined (av) online
        const float sv = accm + accp;
        const float mn = fmaxf(m, sv);
        const float sc = __expf(m - mn);
        const float w  = __expf(sv - mn);
        Z = Z * sc + w;
        S0.x = fmaf(S0.x, sc, w * m0.x);  S0.y = fmaf(S0.y, sc, w * m0.y);
        S0.z = fmaf(S0.z, sc, w * m0.z);  S0.w = fmaf(S0.w, sc, w * m0.w);
        S1.x = fmaf(S1.x, sc, w * m1.x);  S1.y = fmaf(S1.y, sc, w * m1.y);
        S1.z = fmaf(S1.z, sc, w * m1.z);  S1.w = fmaf(S1.w, sc, w * m1.w);
        m = mn;

        // per-branch scalar online stats
        const float mna = fmaxf(Ma, accm);
        Za = Za * __expf(Ma - mna) + __expf(accm - mna);
        Ma = mna;
        const float mnp = fmaxf(Mp, accp);
        Zp = Zp * __expf(Mp - mnp) + __expf(accp - mnp);
        Mp = mnp;
    }

    float* sp = Sbuf + ((size_t)b * NLC + lc) * ND;
    ((float4*)sp)[lane]      = S0;
    ((float4*)sp)[64 + lane] = S1;
    if (lane == 0) {
        const int idx = b * NLC + lc;
        MZ [2*idx] = m;  MZ [2*idx+1] = Z;
        MZa[2*idx] = Ma; MZa[2*idx+1] = Za;
        MZp[2*idx] = Mp; MZp[2*idx+1] = Zp;
    }
}

// ---------------------------------------------------------------------------
// K3: per-b stat combine. One wave per b (16 blocks x 4 waves). Pure shuffles.
// ---------------------------------------------------------------------------
__global__ void __launch_bounds__(256) combineA_kernel(
    const float* __restrict__ MZ, const float* __restrict__ MZa,
    const float* __restrict__ MZp, const int* __restrict__ mem_len,
    float* __restrict__ coef, float* __restrict__ stats)
{
    const int lane = threadIdx.x & 63;
    const int b = blockIdx.x * 4 + (threadIdx.x >> 6);
    const int nv = (mem_len[b] + LC - 1) >> 6;
    const bool v = lane < nv;
    const int idx = b * NLC + lane;
    const float m  = v ? MZ [2*idx] : -1e30f;
    const float z  = v ? MZ [2*idx+1] : 0.f;
    const float ma = v ? MZa[2*idx] : -1e30f;
    const float za = v ? MZa[2*idx+1] : 0.f;
    const float mp = v ? MZp[2*idx] : -1e30f;
    const float zp = v ? MZp[2*idx+1] : 0.f;

    float M = m, A = ma, P = mp;
    #pragma unroll
    for (int off = 32; off; off >>= 1) {
        M = fmaxf(M, __shfl_xor(M, off));
        A = fmaxf(A, __shfl_xor(A, off));
        P = fmaxf(P, __shfl_xor(P, off));
    }
    float ez = z * __expf(m - M);
    float ea = za * __expf(ma - A);
    float ep = zp * __expf(mp - P);
    #pragma unroll
    for (int off = 32; off; off >>= 1) {
        ez += __shfl_xor(ez, off);
        ea += __shfl_xor(ea, off);
        ep += __shfl_xor(ep, off);
    }
    const float invZ = 1.f / ez;
    coef[idx] = v ? __expf(m - M) * invZ : 0.f;
    if (lane == 0) {
        stats[b*8+0] = A;  stats[b*8+1] = 1.f / ea;
        stats[b*8+2] = P;  stats[b*8+3] = 1.f / ep;
        stats[b*8+4] = M;  stats[b*8+5] = invZ;
    }
}

// ---------------------------------------------------------------------------
// K4 (fused): blocks [0,512): c_t = sum_lc coef*S ; blocks [512,1536): finalize
// ---------------------------------------------------------------------------
__global__ void __launch_bounds__(256) combineBF_kernel(
    const float* __restrict__ Sbuf, const float* __restrict__ coef,
    const float* __restrict__ stats, const int* __restrict__ mem_len,
    float* __restrict__ c_t,
    float* __restrict__ a_main, float* __restrict__ a_pos,
    float* __restrict__ out_av)
{
    if (blockIdx.x < 512) {
        __shared__ float sh[4][64];
        const int b = blockIdx.x >> 3, dseg = blockIdx.x & 7;
        const int dl = threadIdx.x & 63, k = threadIdx.x >> 6;
        const int d = dseg * 64 + dl;
        const int nv = (mem_len[b] + LC - 1) >> 6;
        float acc = 0.f;
        for (int lc = k; lc < nv; lc += 4)
            acc = fmaf(coef[b * NLC + lc],
                       Sbuf[((size_t)b * NLC + lc) * ND + d], acc);
        sh[k][dl] = acc;
        __syncthreads();
        if (threadIdx.x < 64)
            c_t[b * ND + dseg * 64 + threadIdx.x] =
                sh[0][threadIdx.x] + sh[1][threadIdx.x] +
                sh[2][threadIdx.x] + sh[3][threadIdx.x];
    } else {
        const int idx = (blockIdx.x - 512) * 256 + threadIdx.x;
        const int b = idx >> 12;
        const int l = idx & (NL - 1);
        const float* st = stats + b * 8;
        const int len = mem_len[b];
        const float a = a_main[idx];
        const float p = a_pos[idx];
        const bool v = l < len;
        a_main[idx] = v ? __expf(a - st[0]) * st[1] : 0.f;
        a_pos [idx] = v ? __expf(p - st[2]) * st[3] : 0.f;
        out_av[idx] = v ? __expf(a + p - st[4]) * st[5] : 0.f;
    }
}

// ---------------------------------------------------------------------------
// K5: attn_h[b,e] = tanh(<[c_t, source], W_out[e,:]>)
// ---------------------------------------------------------------------------
__global__ void __launch_bounds__(256) out_kernel(
    const float* __restrict__ c_t, const float* __restrict__ source,
    const float* __restrict__ Wout, float* __restrict__ attn_h)
{
    __shared__ float cs[2 * ND];
    const int b = blockIdx.x >> 3;
    const int eg = blockIdx.x & 7;
    const int tid = threadIdx.x;

    for (int d = tid; d < ND; d += 256) {
        cs[d] = c_t[b * ND + d];
        cs[ND + d] = source[b * ND + d];
    }
    __syncthreads();

    const int wid = tid >> 6, lane = tid & 63;
    const float4* csv = (const float4*)cs;
    for (int e = eg * 64 + wid; e < eg * 64 + 64; e += 4) {
        const float4* wrow = (const float4*)(Wout + (size_t)e * 2 * ND);
        float acc = 0.f;
        #pragma unroll
        for (int j = 0; j < 4; ++j) {
            const float4 w = wrow[lane + 64 * j];
            const float4 c = csv[lane + 64 * j];
            acc += w.x * c.x + w.y * c.y + w.z * c.z + w.w * c.w;
        }
        #pragma unroll
        for (int off = 32; off; off >>= 1) acc += __shfl_xor(acc, off);
        if (lane == 0) attn_h[(size_t)b * ND + e] = tanhf(acc);
    }
}

// ---------------------------------------------------------------------------
extern "C" void kernel_launch(void* const* d_in, const int* in_sizes, int n_in,
                              void* d_out, int out_size, void* d_ws, size_t ws_size,
                              hipStream_t stream)
{
    const float* source = (const float*)d_in[0];
    const float* me     = (const float*)d_in[1];   // (L, B, D)
    const float* pe     = (const float*)d_in[2];   // (L, B, DP)
    const float* Wmi    = (const float*)d_in[3];   // (D, D)
    const float* Wpi    = (const float*)d_in[4];   // (D, DP)
    const float* Wout   = (const float*)d_in[5];   // (D, 2D)
    const int*   lens   = (const int*)d_in[6];     // (B,)

    float* out    = (float*)d_out;
    float* attn_h = out;                     // (B, D)
    float* av     = attn_h + NB * ND;        // (B, L)
    float* ma     = av + NB * NL;            // (B, L) raw a_main -> in-place
    float* pa     = ma + NB * NL;            // (B, L) raw a_pos  -> in-place

    float* ws    = (float*)d_ws;
    float* qpm   = ws;                              // NB*4*ND   = 131072
    float* qpp   = qpm + NB * 4 * ND;               // NB*4*NDP  = 16384
    float* Sbuf  = qpp + NB * 4 * NDP;              // NB*NLC*ND = 2097152
    float* MZ    = Sbuf + (size_t)NB * NLC * ND;    // NB*NLC*2
    float* MZa   = MZ  + NB * NLC * 2;
    float* MZp   = MZa + NB * NLC * 2;
    float* coef  = MZp + NB * NLC * 2;              // NB*NLC
    float* c_t   = coef + NB * NLC;                 // NB*ND
    float* stats = c_t + NB * ND;                   // NB*8

    queries_kernel <<<NB * 4, 128, 0, stream>>>(source, Wmi, Wpi, qpm, qpp);
    pass1_kernel   <<<NLC * 16, 256, 0, stream>>>(me, pe, qpm, qpp, lens,
                                                  ma, pa, Sbuf, MZ, MZa, MZp);
    combineA_kernel<<<16, 256, 0, stream>>>(MZ, MZa, MZp, lens, coef, stats);
    combineBF_kernel<<<1536, 256, 0, stream>>>(Sbuf, coef, stats, lens,
                                               c_t, ma, pa, av);
    out_kernel     <<<NB * 8, 256, 0, stream>>>(c_t, source, Wout, attn_h);
}